// Round 12
// baseline (2889.032 us; speedup 1.0000x reference)
//
#include <hip/hip_runtime.h>
#include <math.h>

#define B_  64
#define T_  512
#define D0_ 128
#define H_  512
#define G3_ 1536
#define HSTR 512
#define BSTR 528          // bf16-h LDS batch stride (bank-spread: 2-way max)
#define BKg 32
#define SENT 0x7FC00000u   // NaN sentinel; |h|<1 strictly so real h never matches

typedef short short8 __attribute__((ext_vector_type(8)));
typedef float f32x4 __attribute__((ext_vector_type(4)));
typedef unsigned uint32x4 __attribute__((ext_vector_type(4)));

__device__ __forceinline__ float fast_sig(float x) {
  return __builtin_amdgcn_rcpf(1.f + __expf(-x));
}
__device__ __forceinline__ float fast_tanh(float x) {
  // 1 - 2/(1+e^{2x}); saturates correctly at +/-inf
  return 1.f - 2.f * __builtin_amdgcn_rcpf(1.f + __expf(2.f * x));
}

// ---------------- fp32 -> bf16 hi/lo split ----------------
__device__ __forceinline__ unsigned short f2bf_rne(float f) {
  unsigned u = __float_as_uint(f);
  unsigned r = (u + 0x7fffu + ((u >> 16) & 1u)) >> 16;
  return (unsigned short)r;
}
__device__ __forceinline__ float bf2f(unsigned short h) {
  return __uint_as_float(((unsigned)h) << 16);
}

// ---------------- scan kernel (MFMA dot + R22 2-barrier step) -------------
// 256 blocks = 16 groups x 16 blocks; data-as-flag exchange (hist pre-filled
// with SENT; consumers poll h words; producer b32 stores are the signal).
// 768 threads (12 waves).
// FAILED-ATTEMPT LEDGER (do not retry):
//  R12 XCD-colocation: FETCH -57%, dur +4.5% (latency is the coherence RTT).
//  R13 512-block dual-set: poll co-tenancy 2x per-step. R14 s_sleep/pair-
//  store/setprio: +4%. R15 LDS-counter gating: 1.47e9 bank conflicts, 4.7x.
//  R16 same-block dual-layer fusion: 128-VGPR compiler cap -> spill, 2.2x.
//  R17 asm "=v" w/o early-clobber: crash (use "=&v"). R18 quad-poll: NULL.
//  R21 mtile-pairing (ds_read 192->96): NULL (LDS pipe was hidden). Kept.
// R19 WIN (866 -> 568): gh = Whh @ h via mfma_f32_16x16x32_bf16 split-bf16
// 3-product. R20 WIN (568 -> 539): 3 indep acc chains.
// R22: 2-barrier step. (a) hp comes from the gate thread's own register
// (it computed that element last step) -> fp32 hsh staging deleted.
// (b) trailing barrier deleted: pollers are tid in [128,640) (disjoint from
// gate threads tid<128); after bar_B they immediately poll/write hbh/hbl for
// t+1 while gates finish. Hazards: hbh writes(t+1) ordered after MFMA
// reads(t) by bar_B; ghp writes(t+1, after bar_A) ordered after gates
// reads(t, before bar_A). Barrier count uniform -> no deadlock.
// (c) gate threads write their own column's bf16 into LDS directly (skip
// 32/512 polls for t>t0; own data never pays the global RTT).
__global__ __launch_bounds__(768, 3) void scan_kernel(
    const unsigned short* __restrict__ WhH, const unsigned short* __restrict__ WhL,
    const float* __restrict__ bhh,
    const float* __restrict__ gx, float* __restrict__ hist,
    int t0, int tc, int gxt0, int gxT)
{
  __shared__ unsigned short hbh[4 * BSTR];     // h_prev bf16 hi
  __shared__ unsigned short hbl[4 * BSTR];     // h_prev bf16 lo
  __shared__ float ghp[4][96 * 5];             // per-K-quarter gh partials
  __shared__ float bsh[96];

  const int tid = threadIdx.x;
  const int blk = blockIdx.x;
  const int g = blk >> 4, c = blk & 15;   // R11 mapping (measured best)
  const int j0 = c << 5;
  const int bbase = g << 2;

  const int wv = tid >> 6, lane = tid & 63;
  const int q = wv & 3, p = wv >> 2;            // K-quarter, mtile-pair
  const int rloc = lane & 15, kq = lane >> 4;   // A-row-in-tile, k-subgroup
  const int rowA = 32 * p + rloc;               // mtile 2p
  const int rowB = 32 * p + 16 + rloc;          // mtile 2p+1
  const int wrowA = (rowA >> 5) * H_ + j0 + (rowA & 31);
  const int wrowB = (rowB >> 5) * H_ + j0 + (rowB & 31);

  // W fragments: 4 chunks of K=32 within this wave's K-quarter; 2 rows;
  // bf16 hi+lo. 16 x short8 = 64 VGPR.
  short8 whA[4], wlA[4], whB[4], wlB[4];
  {
    const unsigned short* RHA = WhH + (size_t)wrowA * H_ + q * 128 + (kq << 3);
    const unsigned short* RLA = WhL + (size_t)wrowA * H_ + q * 128 + (kq << 3);
    const unsigned short* RHB = WhH + (size_t)wrowB * H_ + q * 128 + (kq << 3);
    const unsigned short* RLB = WhL + (size_t)wrowB * H_ + q * 128 + (kq << 3);
    #pragma unroll
    for (int cc = 0; cc < 4; ++cc) {
      whA[cc] = *(const short8*)(RHA + cc * 32);
      wlA[cc] = *(const short8*)(RLA + cc * 32);
      whB[cc] = *(const short8*)(RHB + cc * 32);
      wlB[cc] = *(const short8*)(RLB + cc * 32);
    }
  }
  if (tid < 96)
    bsh[tid] = bhh[(tid >> 5) * H_ + j0 + (tid & 31)];

  // gate-thread state: own h element in register (R22a)
  float hreg = 0.f;
  size_t go0 = 0;
  if (tid < 128) {
    int bb = tid >> 5, j = tid & 31;
    go0 = ((size_t)(bbase + bb) * gxT) * (size_t)G3_ + j0 + j;
    if (t0 > 0)   // previous dispatch completed -> plain load is coherent
      hreg = hist[((size_t)(bbase + bb) * T_ + (t0 - 1)) * H_ + j0 + j];
  }

  // poller assignment: tid in [128,640) -> 512 quads (4 batches x 128)
  const bool isPoller = (tid >= 128 && tid < 640);
  const int pt = tid - 128;
  const int pbb = pt >> 7, pe4 = pt & 127;
  const bool ownQuad = (pe4 >= (j0 >> 2)) && (pe4 < (j0 >> 2) + 8);

  __syncthreads();

  for (int t = t0; t < t0 + tc; ++t) {
    // ---- staging (t==0: zeros; else pollers poll quads of h[t-1]) ----
    if (t == 0) {
      for (int idx = tid; idx < 4 * BSTR; idx += 768) {
        hbh[idx] = 0; hbl[idx] = 0;
      }
    } else if (isPoller && !(ownQuad && t > t0)) {
      const unsigned* qp = (const unsigned*)
          (hist + ((size_t)(bbase + pbb) * T_ + (t - 1)) * H_) + (pe4 << 2);
      uint32x4 v;
      for (;;) {
        // "=&v" early-clobber: dest must NOT alias addr pair (R17 crash)
        asm volatile(
            "global_load_dwordx4 %0, %1, off sc0 sc1\n\t"
            "s_waitcnt vmcnt(0)"
            : "=&v"(v) : "v"(qp) : "memory");
        if (v.x != SENT && v.y != SENT && v.z != SENT && v.w != SENT) break;
      }
      float fx = __uint_as_float(v.x), fy = __uint_as_float(v.y),
            fz = __uint_as_float(v.z), fw = __uint_as_float(v.w);
      unsigned short h0 = f2bf_rne(fx), h1 = f2bf_rne(fy),
                     h2 = f2bf_rne(fz), h3 = f2bf_rne(fw);
      *(ushort4*)&hbh[pbb * BSTR + (pe4 << 2)] = make_ushort4(h0, h1, h2, h3);
      unsigned short l0 = f2bf_rne(fx - bf2f(h0)), l1 = f2bf_rne(fy - bf2f(h1)),
                     l2 = f2bf_rne(fz - bf2f(h2)), l3 = f2bf_rne(fw - bf2f(h3));
      *(ushort4*)&hbl[pbb * BSTR + (pe4 << 2)] = make_ushort4(l0, l1, l2, l3);
    }
    __syncthreads();   // bar_A: staging complete; ghp(t-1) reads complete

    // ---- gx loads for THIS t (gate threads); latency hides under MFMA ----
    float gxr = 0.f, gxz = 0.f, gxn = 0.f;
    if (tid < 128) {
      size_t go = go0 + (size_t)(t - gxt0) * (size_t)G3_;
      gxr = gx[go]; gxz = gx[go + 512]; gxn = gx[go + 1024];
    }

    // ---- MFMA dot: 2 mtiles share each h-fragment read (R21) ----
    {
      f32x4 aHHA = (f32x4){0.f,0.f,0.f,0.f}, aHLA = aHHA, aLHA = aHHA;
      f32x4 aHHB = aHHA, aHLB = aHHA, aLHB = aHHA;
      const int bb4 = lane & 3;   // batch for this B-col (cols 4-15 duplicate)
      const unsigned short* bhp = hbh + bb4 * BSTR + q * 128 + (kq << 3);
      const unsigned short* blp = hbl + bb4 * BSTR + q * 128 + (kq << 3);
      #pragma unroll
      for (int cc = 0; cc < 4; ++cc) {
        short8 bh = *(const short8*)(bhp + cc * 32);
        short8 bl = *(const short8*)(blp + cc * 32);
        aHHA = __builtin_amdgcn_mfma_f32_16x16x32_bf16(whA[cc], bh, aHHA, 0, 0, 0);
        aHHB = __builtin_amdgcn_mfma_f32_16x16x32_bf16(whB[cc], bh, aHHB, 0, 0, 0);
        aHLA = __builtin_amdgcn_mfma_f32_16x16x32_bf16(whA[cc], bl, aHLA, 0, 0, 0);
        aHLB = __builtin_amdgcn_mfma_f32_16x16x32_bf16(whB[cc], bl, aHLB, 0, 0, 0);
        aLHA = __builtin_amdgcn_mfma_f32_16x16x32_bf16(wlA[cc], bh, aLHA, 0, 0, 0);
        aLHB = __builtin_amdgcn_mfma_f32_16x16x32_bf16(wlB[cc], bh, aLHB, 0, 0, 0);
      }
      f32x4 accA = (aHHA + aHLA) + aLHA;
      f32x4 accB = (aHHB + aHLB) + aLHB;
      // D layout: col = lane&15, row = (lane>>4)*4 + reg. Keep cols 0-3.
      if (rloc < 4) {
        #pragma unroll
        for (int r = 0; r < 4; ++r)
          ghp[q][((2 * p) * 16 + (kq << 2) + r) * 5 + rloc] = accA[r];
        #pragma unroll
        for (int r = 0; r < 4; ++r)
          ghp[q][((2 * p + 1) * 16 + (kq << 2) + r) * 5 + rloc] = accB[r];
      }
    }
    __syncthreads();   // bar_B: ghp ready; hbh/hbl reads complete

    // ---- gates + h_new (tid<128); pollers proceed straight to t+1 polls ----
    if (tid < 128) {
      int bb = tid >> 5, j = tid & 31;
      float ghr = (ghp[0][ j       * 5 + bb] + ghp[1][ j       * 5 + bb]) +
                  (ghp[2][ j       * 5 + bb] + ghp[3][ j       * 5 + bb]) + bsh[j];
      float ghz = (ghp[0][(32 + j) * 5 + bb] + ghp[1][(32 + j) * 5 + bb]) +
                  (ghp[2][(32 + j) * 5 + bb] + ghp[3][(32 + j) * 5 + bb]) + bsh[32 + j];
      float ghn = (ghp[0][(64 + j) * 5 + bb] + ghp[1][(64 + j) * 5 + bb]) +
                  (ghp[2][(64 + j) * 5 + bb] + ghp[3][(64 + j) * 5 + bb]) + bsh[64 + j];
      float rg = fast_sig(gxr + ghr);
      float zg = fast_sig(gxz + ghz);
      float ng = fast_tanh(gxn + rg * ghn);
      float hnew = (1.f - zg) * ng + zg * hreg;
      hreg = hnew;
      __hip_atomic_store(
          (unsigned*)(hist + ((size_t)(bbase + bb) * T_ + t) * H_) + j0 + j,
          __float_as_uint(hnew), __ATOMIC_RELAXED, __HIP_MEMORY_SCOPE_AGENT);
      // R22c: stage own column's bf16 into LDS for step t+1 (read after
      // next bar_A; pollers skip these quads for t>t0)
      unsigned short hh = f2bf_rne(hnew);
      hbh[bb * BSTR + j0 + j] = hh;
      hbl[bb * BSTR + j0 + j] = f2bf_rne(hnew - bf2f(hh));
    }
    // no trailing barrier (R22b): bar_A of t+1 provides the ordering
  }
}

// ---------------- sentinel fill: hist rows [t0, t0+tc) for all batches ----
__global__ __launch_bounds__(256) void sent_fill(float* hist, int t0, int tc) {
  int i = blockIdx.x * 256 + threadIdx.x;          // uint4 index
  int per = tc * (H_ >> 2);                        // uint4 per batch
  if (i < B_ * per) {
    int b = i / per, r = i % per;
    uint4* p = (uint4*)(hist + ((size_t)b * T_ + t0) * H_) + r;
    *p = make_uint4(SENT, SENT, SENT, SENT);
  }
}

__global__ __launch_bounds__(256) void conv_split(
    const float* __restrict__ A, int lda, int t0, int tc, int ltc,
    unsigned short* __restrict__ Ah, unsigned short* __restrict__ Al)
{
  int idx = blockIdx.x * 256 + threadIdx.x;
  int m = idx / (lda >> 2), kq = idx % (lda >> 2);
  const float4 v = *(const float4*)
      (A + ((size_t)(m >> ltc) * T_ + t0 + (m & (tc - 1))) * lda + (kq << 2));
  unsigned short h0 = f2bf_rne(v.x), h1 = f2bf_rne(v.y),
                 h2 = f2bf_rne(v.z), h3 = f2bf_rne(v.w);
  unsigned short l0 = f2bf_rne(v.x - bf2f(h0)), l1 = f2bf_rne(v.y - bf2f(h1)),
                 l2 = f2bf_rne(v.z - bf2f(h2)), l3 = f2bf_rne(v.w - bf2f(h3));
  size_t o = (size_t)m * lda + (kq << 2);
  *(ushort4*)(Ah + o) = make_ushort4(h0, h1, h2, h3);
  *(ushort4*)(Al + o) = make_ushort4(l0, l1, l2, l3);
}

// ---------------- split-bf16 MFMA GEMM (double-buffered, pipelined) -------
__global__ __launch_bounds__(256, 2) void gemm_mfma(
    const unsigned short* __restrict__ Ah, const unsigned short* __restrict__ Al,
    const unsigned short* __restrict__ Bh, const unsigned short* __restrict__ Bl,
    const float* __restrict__ bias, float* __restrict__ gxout, int K)
{
  __shared__ unsigned short sAh[2][128 * BKg], sAl[2][128 * BKg];
  __shared__ unsigned short sBh[2][128 * BKg], sBl[2][128 * BKg];

  const int tid = threadIdx.x;
  const int m0 = blockIdx.x << 7, n0 = blockIdx.y << 7;
  const int wave = tid >> 6, lane = tid & 63;
  const int wr = (wave & 1) << 6, wc = (wave >> 1) << 6;
  const int fm = lane & 15, kh = lane >> 4;

  const int srow = tid >> 2, sq = tid & 3;
  const int lofs0 = srow * BKg + (sq << 3);
  const int lofs1 = (64 + srow) * BKg + (sq << 3);

  f32x4 acc[4][4];
  #pragma unroll
  for (int i = 0; i < 4; ++i)
    #pragma unroll
    for (int j = 0; j < 4; ++j)
      acc[i][j] = (f32x4){0.f, 0.f, 0.f, 0.f};

  float4 pAh[2], pAl[2], pBh[2], pBl[2];
  #define PREFETCH(k0)                                                        \
    {                                                                         \
      size_t a0 = (size_t)(m0 + srow) * K + (k0) + (sq << 3);                 \
      size_t a1 = (size_t)(m0 + 64 + srow) * K + (k0) + (sq << 3);            \
      size_t b0 = (size_t)(n0 + srow) * K + (k0) + (sq << 3);                 \
      size_t b1 = (size_t)(n0 + 64 + srow) * K + (k0) + (sq << 3);            \
      pAh[0] = *(const float4*)&Ah[a0]; pAh[1] = *(const float4*)&Ah[a1];     \
      pAl[0] = *(const float4*)&Al[a0]; pAl[1] = *(const float4*)&Al[a1];     \
      pBh[0] = *(const float4*)&Bh[b0]; pBh[1] = *(const float4*)&Bh[b1];     \
      pBl[0] = *(const float4*)&Bl[b0]; pBl[1] = *(const float4*)&Bl[b1];     \
    }
  #define STORE_LDS(buf)                                                      \
    {                                                                         \
      *(float4*)&sAh[buf][lofs0] = pAh[0]; *(float4*)&sAh[buf][lofs1] = pAh[1];\
      *(float4*)&sAl[buf][lofs0] = pAl[0]; *(float4*)&sAl[buf][lofs1] = pAl[1];\
      *(float4*)&sBh[buf][lofs0] = pBh[0]; *(float4*)&sBh[buf][lofs1] = pBh[1];\
      *(float4*)&sBl[buf][lofs0] = pBl[0]; *(float4*)&sBl[buf][lofs1] = pBl[1];\
    }

  PREFETCH(0);
  STORE_LDS(0);
  int buf = 0;

  for (int k0 = 0; k0 < K; k0 += BKg) {
    __syncthreads();
    const bool more = (k0 + BKg) < K;
    if (more) PREFETCH(k0 + BKg);

    short8 fAh[4], fAl[4], fBh[4], fBl[4];
    #pragma unroll
    for (int i = 0; i < 4; ++i) {
      int ao = (wr + i * 16 + fm) * BKg + (kh << 3);
      int bo = (wc + i * 16 + fm) * BKg + (kh << 3);
      fAh[i] = *(const short8*)&sAh[buf][ao];
      fAl[i] = *(const short8*)&sAl[buf][ao];
      fBh[i] = *(const short8*)&sBh[buf][bo];
      fBl[i] = *(const short8*)&sBl[buf][bo];
    }
    #pragma unroll
    for (int i = 0; i < 4; ++i)
      #pragma unroll
      for (int j = 0; j < 4; ++j) {
        acc[i][j] = __builtin_amdgcn_mfma_f32_16x16x32_bf16(
            fAh[i], fBh[j], acc[i][j], 0, 0, 0);
        acc[i][j] = __builtin_amdgcn_mfma_f32_16x16x32_bf16(
            fAh[i], fBl[j], acc[i][j], 0, 0, 0);
        acc[i][j] = __builtin_amdgcn_mfma_f32_16x16x32_bf16(
            fAl[i], fBh[j], acc[i][j], 0, 0, 0);
      }
    if (more) {
      STORE_LDS(buf ^ 1);
      buf ^= 1;
    }
  }

  #pragma unroll
  for (int j = 0; j < 4; ++j) {
    int col = n0 + wc + j * 16 + fm;
    float bv = bias[col];
    #pragma unroll
    for (int i = 0; i < 4; ++i) {
      int rowb = m0 + wr + i * 16 + (kh << 2);
      #pragma unroll
      for (int r = 0; r < 4; ++r)
        gxout[(size_t)(rowb + r) * G3_ + col] = acc[i][j][r] + bv;
    }
  }
}

// ---------------- final FC ----------------
__global__ void fc_kernel(const float* __restrict__ hist, const float* __restrict__ Wfc,
                          const float* __restrict__ bfc, float* __restrict__ out)
{
  int b = blockIdx.x, lane = threadIdx.x;
  const float* h = hist + ((size_t)b*T_ + (T_-1))*H_;
  float acc = 0.f;
  for (int j = lane; j < H_; j += 64) acc += h[j]*Wfc[j];
  #pragma unroll
  for (int off = 32; off; off >>= 1) acc += __shfl_down(acc, off, 64);
  if (lane == 0) out[b] = acc + bfc[0];
}

extern "C" void kernel_launch(void* const* d_in, const int* in_sizes, int n_in,
                              void* d_out, int out_size, void* d_ws, size_t ws_size,
                              hipStream_t stream)
{
  const float* X    = (const float*)d_in[0];
  const float* Wih0 = (const float*)d_in[1];
  const float* Whh0 = (const float*)d_in[2];
  const float* bih0 = (const float*)d_in[3];
  const float* bhh0 = (const float*)d_in[4];
  const float* Wih1 = (const float*)d_in[5];
  const float* Whh1 = (const float*)d_in[6];
  const float* bih1 = (const float*)d_in[7];
  const float* bhh1 = (const float*)d_in[8];
  const float* Wfc  = (const float*)d_in[9];
  const float* bfc  = (const float*)d_in[10];

  float* hist = (float*)((char*)d_ws + 4096);
  const size_t histB = (size_t)B_*T_*H_*4;

  const size_t bB = (size_t)G3_ * 512 * 2;   // Wih split (hi or lo)
  const size_t wB = (size_t)G3_ * H_ * 2;    // Whh split (hi or lo)
  int tcg = 128;
  {
    size_t fixed = 4096 + histB + 2 * bB + 2 * wB;
    if      (ws_size >= fixed + (size_t)B_*512*((size_t)G3_*4 + 512*4)) tcg = 512;
    else if (ws_size >= fixed + (size_t)B_*256*((size_t)G3_*4 + 512*4)) tcg = 256;
  }
  int ltc = 31 - __builtin_clz((unsigned)tcg);

  float* gxbuf = (float*)((char*)d_ws + 4096 + histB);
  const size_t gxB = (size_t)B_*tcg*G3_*4;
  unsigned short* Ahb = (unsigned short*)((char*)gxbuf + gxB);
  const size_t aB = (size_t)B_*tcg*512*2;
  unsigned short* Alb = (unsigned short*)((char*)Ahb + aB);
  unsigned short* Bhb = (unsigned short*)((char*)Alb + aB);
  unsigned short* Blb = (unsigned short*)((char*)Bhb + bB);
  unsigned short* Whb = (unsigned short*)((char*)Blb + bB);
  unsigned short* Wlb = (unsigned short*)((char*)Whb + wB);

  const int sentGridFull = (B_ * T_ * (H_ >> 2) + 255) / 256;
  const int sentGridChunk = (B_ * tcg * (H_ >> 2) + 255) / 256;

  // layer 0: whole hist -> sentinel before its first scan (conv/gemm read X)
  hipLaunchKernelGGL(sent_fill, dim3(sentGridFull), dim3(256), 0, stream,
                     hist, 0, T_);

  for (int lay = 0; lay < 2; ++lay) {
    const float* A   = lay ? (const float*)hist : X;
    int lda          = lay ? H_ : D0_;
    const float* Wih = lay ? Wih1 : Wih0;
    const float* bih = lay ? bih1 : bih0;
    const float* Whh = lay ? Whh1 : Whh0;
    const float* bhh = lay ? bhh1 : bhh0;

    hipLaunchKernelGGL(conv_split, dim3((G3_*lda/4)/256), dim3(256), 0, stream,
                       Wih, lda, 0, 1 << 30, 30, Bhb, Blb);
    // Whh -> bf16 hi/lo for the scan's MFMA dot (R19)
    hipLaunchKernelGGL(conv_split, dim3((G3_*H_/4)/256), dim3(256), 0, stream,
                       Whh, H_, 0, 1 << 30, 30, Whb, Wlb);

    for (int t0g = 0; t0g < T_; t0g += tcg) {
      int M = B_ * tcg;
      // conv reads this chunk's hist rows (layer 1) BEFORE they're sentineled
      hipLaunchKernelGGL(conv_split, dim3((M*lda/4)/256), dim3(256), 0, stream,
                         A, lda, t0g, tcg, ltc, Ahb, Alb);
      if (lay == 1)   // re-sentinel the rows this chunk's scan will write
        hipLaunchKernelGGL(sent_fill, dim3(sentGridChunk), dim3(256), 0, stream,
                           hist, t0g, tcg);
      dim3 ggrid(M >> 7, G3_ >> 7);
      hipLaunchKernelGGL(gemm_mfma, ggrid, dim3(256), 0, stream,
                         Ahb, Alb, Bhb, Blb, bih, gxbuf, lda);
      hipLaunchKernelGGL(scan_kernel, dim3(256), dim3(768), 0, stream,
                         Whb, Wlb, bhh, (const float*)gxbuf, hist,
                         t0g, tcg, t0g, tcg);
    }
  }

  hipLaunchKernelGGL(fc_kernel, dim3(64), dim3(64), 0, stream,
                     (const float*)hist, Wfc, bfc, (float*)d_out);
}

// Round 13
// 2559.310 us; speedup vs baseline: 1.1288x; 1.1288x over previous
//
#include <hip/hip_runtime.h>
#include <math.h>

#define B_  64
#define T_  512
#define D0_ 128
#define H_  512
#define G3_ 1536
#define HSTR 512
#define BSTR 528          // bf16-h LDS batch stride (bank-spread: 2-way max)
#define BKg 32
#define SENT 0x7FC00000u   // NaN sentinel; |h|<1 strictly so real h never matches

typedef short short8 __attribute__((ext_vector_type(8)));
typedef float f32x4 __attribute__((ext_vector_type(4)));
typedef unsigned uint32x4 __attribute__((ext_vector_type(4)));

__device__ __forceinline__ float fast_sig(float x) {
  return __builtin_amdgcn_rcpf(1.f + __expf(-x));
}
__device__ __forceinline__ float fast_tanh(float x) {
  // 1 - 2/(1+e^{2x}); saturates correctly at +/-inf
  return 1.f - 2.f * __builtin_amdgcn_rcpf(1.f + __expf(2.f * x));
}

// ---------------- fp32 -> bf16 hi/lo split ----------------
__device__ __forceinline__ unsigned short f2bf_rne(float f) {
  unsigned u = __float_as_uint(f);
  unsigned r = (u + 0x7fffu + ((u >> 16) & 1u)) >> 16;
  return (unsigned short)r;
}
__device__ __forceinline__ float bf2f(unsigned short h) {
  return __uint_as_float(((unsigned)h) << 16);
}

// ---------------- scan kernel (R21 structure + safe R22 pieces) -----------
// 256 blocks = 16 groups x 16 blocks; data-as-flag exchange (hist pre-filled
// with SENT; consumers poll h words; producer b32 stores are the signal).
// 768 threads (12 waves).
// FAILED-ATTEMPT LEDGER (do not retry):
//  R12 XCD-colocation: FETCH -57%, dur +4.5% (latency is the coherence RTT).
//  R13 512-block dual-set: poll co-tenancy 2x per-step. R14 s_sleep/pair-
//  store/setprio: +4%. R15 LDS-counter gating: 1.47e9 bank conflicts, 4.7x.
//  R16 same-block dual-layer fusion: 128-VGPR compiler cap -> spill, 2.2x.
//  R17 asm "=v" w/o early-clobber: crash (use "=&v"). R18 quad-poll: NULL.
//  R21 mtile-pairing (ds_read 192->96): NULL (LDS pipe hidden). Kept.
//  R22b EARLY POLLS (no trailing barrier): FETCH +45%, dur +16% -- polls
//      must NOT start before producers store (3rd confirmation of R10).
// R19 WIN (866 -> 568): gh = Whh @ h via mfma_f32_16x16x32_bf16 split-bf16
// 3-product. R20 WIN (568 -> 539): 3 indep acc chains.
// R23: R21 barriers/poll placement EXACTLY + safe R22 pieces: (a) hp from
// gate thread's own register (fp32 hsh deleted); (c) gate threads stage own
// column's bf16 into LDS; pollers skip those 8 quads for t>t0.
__global__ __launch_bounds__(768, 3) void scan_kernel(
    const unsigned short* __restrict__ WhH, const unsigned short* __restrict__ WhL,
    const float* __restrict__ bhh,
    const float* __restrict__ gx, float* __restrict__ hist,
    int t0, int tc, int gxt0, int gxT)
{
  __shared__ unsigned short hbh[4 * BSTR];     // h_prev bf16 hi
  __shared__ unsigned short hbl[4 * BSTR];     // h_prev bf16 lo
  __shared__ float ghp[4][96 * 5];             // per-K-quarter gh partials
  __shared__ float bsh[96];

  const int tid = threadIdx.x;
  const int blk = blockIdx.x;
  const int g = blk >> 4, c = blk & 15;   // R11 mapping (measured best)
  const int j0 = c << 5;
  const int bbase = g << 2;

  const int wv = tid >> 6, lane = tid & 63;
  const int q = wv & 3, p = wv >> 2;            // K-quarter, mtile-pair
  const int rloc = lane & 15, kq = lane >> 4;   // A-row-in-tile, k-subgroup
  const int rowA = 32 * p + rloc;               // mtile 2p
  const int rowB = 32 * p + 16 + rloc;          // mtile 2p+1
  const int wrowA = (rowA >> 5) * H_ + j0 + (rowA & 31);
  const int wrowB = (rowB >> 5) * H_ + j0 + (rowB & 31);

  // W fragments: 4 chunks of K=32 within this wave's K-quarter; 2 rows;
  // bf16 hi+lo. 16 x short8 = 64 VGPR.
  short8 whA[4], wlA[4], whB[4], wlB[4];
  {
    const unsigned short* RHA = WhH + (size_t)wrowA * H_ + q * 128 + (kq << 3);
    const unsigned short* RLA = WhL + (size_t)wrowA * H_ + q * 128 + (kq << 3);
    const unsigned short* RHB = WhH + (size_t)wrowB * H_ + q * 128 + (kq << 3);
    const unsigned short* RLB = WhL + (size_t)wrowB * H_ + q * 128 + (kq << 3);
    #pragma unroll
    for (int cc = 0; cc < 4; ++cc) {
      whA[cc] = *(const short8*)(RHA + cc * 32);
      wlA[cc] = *(const short8*)(RLA + cc * 32);
      whB[cc] = *(const short8*)(RHB + cc * 32);
      wlB[cc] = *(const short8*)(RLB + cc * 32);
    }
  }
  if (tid < 96)
    bsh[tid] = bhh[(tid >> 5) * H_ + j0 + (tid & 31)];

  // gate-thread state: own h element in register (R22a)
  float hreg = 0.f;
  size_t go0 = 0;
  if (tid < 128) {
    int bb = tid >> 5, j = tid & 31;
    go0 = ((size_t)(bbase + bb) * gxT) * (size_t)G3_ + j0 + j;
    if (t0 > 0)   // previous dispatch completed; coherent read of h[t0-1]
      hreg = __uint_as_float(__hip_atomic_load(
          (const unsigned*)(hist +
              ((size_t)(bbase + bb) * T_ + (t0 - 1)) * H_) + j0 + j,
          __ATOMIC_RELAXED, __HIP_MEMORY_SCOPE_AGENT));
  }

  // poller mapping (R21): tid<512, quad per thread
  const int pbb = tid >> 7, pe4 = tid & 127;
  const bool ownQuad = (pe4 >= (j0 >> 2)) && (pe4 < (j0 >> 2) + 8);

  __syncthreads();

  for (int t = t0; t < t0 + tc; ++t) {
    // ---- staging (t==0: zeros; else pollers poll quads of h[t-1]) ----
    if (t == 0) {
      for (int idx = tid; idx < 4 * BSTR; idx += 768) {
        hbh[idx] = 0; hbl[idx] = 0;
      }
    } else if (tid < 512 && !(ownQuad && t > t0)) {
      const unsigned* qp = (const unsigned*)
          (hist + ((size_t)(bbase + pbb) * T_ + (t - 1)) * H_) + (pe4 << 2);
      uint32x4 v;
      for (;;) {
        // "=&v" early-clobber: dest must NOT alias addr pair (R17 crash)
        asm volatile(
            "global_load_dwordx4 %0, %1, off sc0 sc1\n\t"
            "s_waitcnt vmcnt(0)"
            : "=&v"(v) : "v"(qp) : "memory");
        if (v.x != SENT && v.y != SENT && v.z != SENT && v.w != SENT) break;
      }
      float fx = __uint_as_float(v.x), fy = __uint_as_float(v.y),
            fz = __uint_as_float(v.z), fw = __uint_as_float(v.w);
      unsigned short h0 = f2bf_rne(fx), h1 = f2bf_rne(fy),
                     h2 = f2bf_rne(fz), h3 = f2bf_rne(fw);
      *(ushort4*)&hbh[pbb * BSTR + (pe4 << 2)] = make_ushort4(h0, h1, h2, h3);
      unsigned short l0 = f2bf_rne(fx - bf2f(h0)), l1 = f2bf_rne(fy - bf2f(h1)),
                     l2 = f2bf_rne(fz - bf2f(h2)), l3 = f2bf_rne(fw - bf2f(h3));
      *(ushort4*)&hbl[pbb * BSTR + (pe4 << 2)] = make_ushort4(l0, l1, l2, l3);
    }

    // ---- gx loads (gate threads); latency hides under the dot ----
    float gxr = 0.f, gxz = 0.f, gxn = 0.f;
    if (tid < 128) {
      size_t go = go0 + (size_t)(t - gxt0) * (size_t)G3_;
      gxr = gx[go]; gxz = gx[go + 512]; gxn = gx[go + 1024];
    }
    __syncthreads();   // bar_A: staging complete

    // ---- MFMA dot: 2 mtiles share each h-fragment read (R21) ----
    {
      f32x4 aHHA = (f32x4){0.f,0.f,0.f,0.f}, aHLA = aHHA, aLHA = aHHA;
      f32x4 aHHB = aHHA, aHLB = aHHA, aLHB = aHHA;
      const int bb4 = lane & 3;   // batch for this B-col (cols 4-15 duplicate)
      const unsigned short* bhp = hbh + bb4 * BSTR + q * 128 + (kq << 3);
      const unsigned short* blp = hbl + bb4 * BSTR + q * 128 + (kq << 3);
      #pragma unroll
      for (int cc = 0; cc < 4; ++cc) {
        short8 bh = *(const short8*)(bhp + cc * 32);
        short8 bl = *(const short8*)(blp + cc * 32);
        aHHA = __builtin_amdgcn_mfma_f32_16x16x32_bf16(whA[cc], bh, aHHA, 0, 0, 0);
        aHHB = __builtin_amdgcn_mfma_f32_16x16x32_bf16(whB[cc], bh, aHHB, 0, 0, 0);
        aHLA = __builtin_amdgcn_mfma_f32_16x16x32_bf16(whA[cc], bl, aHLA, 0, 0, 0);
        aHLB = __builtin_amdgcn_mfma_f32_16x16x32_bf16(whB[cc], bl, aHLB, 0, 0, 0);
        aLHA = __builtin_amdgcn_mfma_f32_16x16x32_bf16(wlA[cc], bh, aLHA, 0, 0, 0);
        aLHB = __builtin_amdgcn_mfma_f32_16x16x32_bf16(wlB[cc], bh, aLHB, 0, 0, 0);
      }
      f32x4 accA = (aHHA + aHLA) + aLHA;
      f32x4 accB = (aHHB + aHLB) + aLHB;
      // D layout: col = lane&15, row = (lane>>4)*4 + reg. Keep cols 0-3.
      if (rloc < 4) {
        #pragma unroll
        for (int r = 0; r < 4; ++r)
          ghp[q][((2 * p) * 16 + (kq << 2) + r) * 5 + rloc] = accA[r];
        #pragma unroll
        for (int r = 0; r < 4; ++r)
          ghp[q][((2 * p + 1) * 16 + (kq << 2) + r) * 5 + rloc] = accB[r];
      }
    }
    __syncthreads();   // bar_B: ghp ready; hbh/hbl reads complete

    // ---- gates + h_new (tid<128); own-column bf16 staged locally ----
    if (tid < 128) {
      int bb = tid >> 5, j = tid & 31;
      float ghr = (ghp[0][ j       * 5 + bb] + ghp[1][ j       * 5 + bb]) +
                  (ghp[2][ j       * 5 + bb] + ghp[3][ j       * 5 + bb]) + bsh[j];
      float ghz = (ghp[0][(32 + j) * 5 + bb] + ghp[1][(32 + j) * 5 + bb]) +
                  (ghp[2][(32 + j) * 5 + bb] + ghp[3][(32 + j) * 5 + bb]) + bsh[32 + j];
      float ghn = (ghp[0][(64 + j) * 5 + bb] + ghp[1][(64 + j) * 5 + bb]) +
                  (ghp[2][(64 + j) * 5 + bb] + ghp[3][(64 + j) * 5 + bb]) + bsh[64 + j];
      float rg = fast_sig(gxr + ghr);
      float zg = fast_sig(gxz + ghz);
      float ng = fast_tanh(gxn + rg * ghn);
      float hnew = (1.f - zg) * ng + zg * hreg;
      hreg = hnew;
      __hip_atomic_store(
          (unsigned*)(hist + ((size_t)(bbase + bb) * T_ + t) * H_) + j0 + j,
          __float_as_uint(hnew), __ATOMIC_RELAXED, __HIP_MEMORY_SCOPE_AGENT);
      // R22c: stage own column's bf16 for step t+1 (pollers skip these
      // quads for t>t0; ordered vs next MFMA reads by bar_C -> bar_A)
      unsigned short hh = f2bf_rne(hnew);
      hbh[bb * BSTR + j0 + j] = hh;
      hbl[bb * BSTR + j0 + j] = f2bf_rne(hnew - bf2f(hh));
    }
    __syncthreads();   // bar_C: R10/R22b lesson -- polls must NOT start early
  }
}

// ---------------- sentinel fill: hist rows [t0, t0+tc) for all batches ----
__global__ __launch_bounds__(256) void sent_fill(float* hist, int t0, int tc) {
  int i = blockIdx.x * 256 + threadIdx.x;          // uint4 index
  int per = tc * (H_ >> 2);                        // uint4 per batch
  if (i < B_ * per) {
    int b = i / per, r = i % per;
    uint4* p = (uint4*)(hist + ((size_t)b * T_ + t0) * H_) + r;
    *p = make_uint4(SENT, SENT, SENT, SENT);
  }
}

__global__ __launch_bounds__(256) void conv_split(
    const float* __restrict__ A, int lda, int t0, int tc, int ltc,
    unsigned short* __restrict__ Ah, unsigned short* __restrict__ Al)
{
  int idx = blockIdx.x * 256 + threadIdx.x;
  int m = idx / (lda >> 2), kq = idx % (lda >> 2);
  const float4 v = *(const float4*)
      (A + ((size_t)(m >> ltc) * T_ + t0 + (m & (tc - 1))) * lda + (kq << 2));
  unsigned short h0 = f2bf_rne(v.x), h1 = f2bf_rne(v.y),
                 h2 = f2bf_rne(v.z), h3 = f2bf_rne(v.w);
  unsigned short l0 = f2bf_rne(v.x - bf2f(h0)), l1 = f2bf_rne(v.y - bf2f(h1)),
                 l2 = f2bf_rne(v.z - bf2f(h2)), l3 = f2bf_rne(v.w - bf2f(h3));
  size_t o = (size_t)m * lda + (kq << 2);
  *(ushort4*)(Ah + o) = make_ushort4(h0, h1, h2, h3);
  *(ushort4*)(Al + o) = make_ushort4(l0, l1, l2, l3);
}

// ---------------- split-bf16 MFMA GEMM (double-buffered, pipelined) -------
__global__ __launch_bounds__(256, 2) void gemm_mfma(
    const unsigned short* __restrict__ Ah, const unsigned short* __restrict__ Al,
    const unsigned short* __restrict__ Bh, const unsigned short* __restrict__ Bl,
    const float* __restrict__ bias, float* __restrict__ gxout, int K)
{
  __shared__ unsigned short sAh[2][128 * BKg], sAl[2][128 * BKg];
  __shared__ unsigned short sBh[2][128 * BKg], sBl[2][128 * BKg];

  const int tid = threadIdx.x;
  const int m0 = blockIdx.x << 7, n0 = blockIdx.y << 7;
  const int wave = tid >> 6, lane = tid & 63;
  const int wr = (wave & 1) << 6, wc = (wave >> 1) << 6;
  const int fm = lane & 15, kh = lane >> 4;

  const int srow = tid >> 2, sq = tid & 3;
  const int lofs0 = srow * BKg + (sq << 3);
  const int lofs1 = (64 + srow) * BKg + (sq << 3);

  f32x4 acc[4][4];
  #pragma unroll
  for (int i = 0; i < 4; ++i)
    #pragma unroll
    for (int j = 0; j < 4; ++j)
      acc[i][j] = (f32x4){0.f, 0.f, 0.f, 0.f};

  float4 pAh[2], pAl[2], pBh[2], pBl[2];
  #define PREFETCH(k0)                                                        \
    {                                                                         \
      size_t a0 = (size_t)(m0 + srow) * K + (k0) + (sq << 3);                 \
      size_t a1 = (size_t)(m0 + 64 + srow) * K + (k0) + (sq << 3);            \
      size_t b0 = (size_t)(n0 + srow) * K + (k0) + (sq << 3);                 \
      size_t b1 = (size_t)(n0 + 64 + srow) * K + (k0) + (sq << 3);            \
      pAh[0] = *(const float4*)&Ah[a0]; pAh[1] = *(const float4*)&Ah[a1];     \
      pAl[0] = *(const float4*)&Al[a0]; pAl[1] = *(const float4*)&Al[a1];     \
      pBh[0] = *(const float4*)&Bh[b0]; pBh[1] = *(const float4*)&Bh[b1];     \
      pBl[0] = *(const float4*)&Bl[b0]; pBl[1] = *(const float4*)&Bl[b1];     \
    }
  #define STORE_LDS(buf)                                                      \
    {                                                                         \
      *(float4*)&sAh[buf][lofs0] = pAh[0]; *(float4*)&sAh[buf][lofs1] = pAh[1];\
      *(float4*)&sAl[buf][lofs0] = pAl[0]; *(float4*)&sAl[buf][lofs1] = pAl[1];\
      *(float4*)&sBh[buf][lofs0] = pBh[0]; *(float4*)&sBh[buf][lofs1] = pBh[1];\
      *(float4*)&sBl[buf][lofs0] = pBl[0]; *(float4*)&sBl[buf][lofs1] = pBl[1];\
    }

  PREFETCH(0);
  STORE_LDS(0);
  int buf = 0;

  for (int k0 = 0; k0 < K; k0 += BKg) {
    __syncthreads();
    const bool more = (k0 + BKg) < K;
    if (more) PREFETCH(k0 + BKg);

    short8 fAh[4], fAl[4], fBh[4], fBl[4];
    #pragma unroll
    for (int i = 0; i < 4; ++i) {
      int ao = (wr + i * 16 + fm) * BKg + (kh << 3);
      int bo = (wc + i * 16 + fm) * BKg + (kh << 3);
      fAh[i] = *(const short8*)&sAh[buf][ao];
      fAl[i] = *(const short8*)&sAl[buf][ao];
      fBh[i] = *(const short8*)&sBh[buf][bo];
      fBl[i] = *(const short8*)&sBl[buf][bo];
    }
    #pragma unroll
    for (int i = 0; i < 4; ++i)
      #pragma unroll
      for (int j = 0; j < 4; ++j) {
        acc[i][j] = __builtin_amdgcn_mfma_f32_16x16x32_bf16(
            fAh[i], fBh[j], acc[i][j], 0, 0, 0);
        acc[i][j] = __builtin_amdgcn_mfma_f32_16x16x32_bf16(
            fAh[i], fBl[j], acc[i][j], 0, 0, 0);
        acc[i][j] = __builtin_amdgcn_mfma_f32_16x16x32_bf16(
            fAl[i], fBh[j], acc[i][j], 0, 0, 0);
      }
    if (more) {
      STORE_LDS(buf ^ 1);
      buf ^= 1;
    }
  }

  #pragma unroll
  for (int j = 0; j < 4; ++j) {
    int col = n0 + wc + j * 16 + fm;
    float bv = bias[col];
    #pragma unroll
    for (int i = 0; i < 4; ++i) {
      int rowb = m0 + wr + i * 16 + (kh << 2);
      #pragma unroll
      for (int r = 0; r < 4; ++r)
        gxout[(size_t)(rowb + r) * G3_ + col] = acc[i][j][r] + bv;
    }
  }
}

// ---------------- final FC ----------------
__global__ void fc_kernel(const float* __restrict__ hist, const float* __restrict__ Wfc,
                          const float* __restrict__ bfc, float* __restrict__ out)
{
  int b = blockIdx.x, lane = threadIdx.x;
  const float* h = hist + ((size_t)b*T_ + (T_-1))*H_;
  float acc = 0.f;
  for (int j = lane; j < H_; j += 64) acc += h[j]*Wfc[j];
  #pragma unroll
  for (int off = 32; off; off >>= 1) acc += __shfl_down(acc, off, 64);
  if (lane == 0) out[b] = acc + bfc[0];
}

extern "C" void kernel_launch(void* const* d_in, const int* in_sizes, int n_in,
                              void* d_out, int out_size, void* d_ws, size_t ws_size,
                              hipStream_t stream)
{
  const float* X    = (const float*)d_in[0];
  const float* Wih0 = (const float*)d_in[1];
  const float* Whh0 = (const float*)d_in[2];
  const float* bih0 = (const float*)d_in[3];
  const float* bhh0 = (const float*)d_in[4];
  const float* Wih1 = (const float*)d_in[5];
  const float* Whh1 = (const float*)d_in[6];
  const float* bih1 = (const float*)d_in[7];
  const float* bhh1 = (const float*)d_in[8];
  const float* Wfc  = (const float*)d_in[9];
  const float* bfc  = (const float*)d_in[10];

  float* hist = (float*)((char*)d_ws + 4096);
  const size_t histB = (size_t)B_*T_*H_*4;

  const size_t bB = (size_t)G3_ * 512 * 2;   // Wih split (hi or lo)
  const size_t wB = (size_t)G3_ * H_ * 2;    // Whh split (hi or lo)
  int tcg = 128;
  {
    size_t fixed = 4096 + histB + 2 * bB + 2 * wB;
    if      (ws_size >= fixed + (size_t)B_*512*((size_t)G3_*4 + 512*4)) tcg = 512;
    else if (ws_size >= fixed + (size_t)B_*256*((size_t)G3_*4 + 512*4)) tcg = 256;
  }
  int ltc = 31 - __builtin_clz((unsigned)tcg);

  float* gxbuf = (float*)((char*)d_ws + 4096 + histB);
  const size_t gxB = (size_t)B_*tcg*G3_*4;
  unsigned short* Ahb = (unsigned short*)((char*)gxbuf + gxB);
  const size_t aB = (size_t)B_*tcg*512*2;
  unsigned short* Alb = (unsigned short*)((char*)Ahb + aB);
  unsigned short* Bhb = (unsigned short*)((char*)Alb + aB);
  unsigned short* Blb = (unsigned short*)((char*)Bhb + bB);
  unsigned short* Whb = (unsigned short*)((char*)Blb + bB);
  unsigned short* Wlb = (unsigned short*)((char*)Whb + wB);

  const int sentGridFull = (B_ * T_ * (H_ >> 2) + 255) / 256;
  const int sentGridChunk = (B_ * tcg * (H_ >> 2) + 255) / 256;

  // layer 0: whole hist -> sentinel before its first scan (conv/gemm read X)
  hipLaunchKernelGGL(sent_fill, dim3(sentGridFull), dim3(256), 0, stream,
                     hist, 0, T_);

  for (int lay = 0; lay < 2; ++lay) {
    const float* A   = lay ? (const float*)hist : X;
    int lda          = lay ? H_ : D0_;
    const float* Wih = lay ? Wih1 : Wih0;
    const float* bih = lay ? bih1 : bih0;
    const float* Whh = lay ? Whh1 : Whh0;
    const float* bhh = lay ? bhh1 : bhh0;

    hipLaunchKernelGGL(conv_split, dim3((G3_*lda/4)/256), dim3(256), 0, stream,
                       Wih, lda, 0, 1 << 30, 30, Bhb, Blb);
    // Whh -> bf16 hi/lo for the scan's MFMA dot (R19)
    hipLaunchKernelGGL(conv_split, dim3((G3_*H_/4)/256), dim3(256), 0, stream,
                       Whh, H_, 0, 1 << 30, 30, Whb, Wlb);

    for (int t0g = 0; t0g < T_; t0g += tcg) {
      int M = B_ * tcg;
      // conv reads this chunk's hist rows (layer 1) BEFORE they're sentineled
      hipLaunchKernelGGL(conv_split, dim3((M*lda/4)/256), dim3(256), 0, stream,
                         A, lda, t0g, tcg, ltc, Ahb, Alb);
      if (lay == 1)   // re-sentinel the rows this chunk's scan will write
        hipLaunchKernelGGL(sent_fill, dim3(sentGridChunk), dim3(256), 0, stream,
                           hist, t0g, tcg);
      dim3 ggrid(M >> 7, G3_ >> 7);
      hipLaunchKernelGGL(gemm_mfma, ggrid, dim3(256), 0, stream,
                         Ahb, Alb, Bhb, Blb, bih, gxbuf, lda);
      hipLaunchKernelGGL(scan_kernel, dim3(256), dim3(768), 0, stream,
                         Whb, Wlb, bhh, (const float*)gxbuf, hist,
                         t0g, tcg, t0g, tcg);
    }
  }

  hipLaunchKernelGGL(fc_kernel, dim3(64), dim3(64), 0, stream,
                     (const float*)hist, Wfc, bfc, (float*)d_out);
}